// Round 6
// baseline (176.594 us; speedup 1.0000x reference)
//
#include <hip/hip_runtime.h>
#include <math.h>

// Problem constants: B=2, S=T=2048, E=1024, H=16, D=64
typedef __attribute__((ext_vector_type(8))) short short8;
typedef __attribute__((ext_vector_type(4))) float f32x4;
typedef unsigned short u16;

// fp32 -> bf16 round-to-nearest-even (finite inputs)
__device__ __forceinline__ u16 f2bf(float x) {
    unsigned int u = __float_as_uint(x);
    u += 0x7FFFu + ((u >> 16) & 1u);
    return (u16)(u >> 16);
}

__device__ __forceinline__ void load_lds16(const void* g, void* l) {
    __builtin_amdgcn_global_load_lds(
        (const __attribute__((address_space(1))) unsigned int*)g,
        (__attribute__((address_space(3))) unsigned int*)l,
        16, 0, 0);
}

// ---------------------------------------------------------------------------
// Batched fp32 -> bf16 convert (7 tensors)
// ---------------------------------------------------------------------------
struct CvtArgs {
    const float* src[7];
    u16* dst[7];
    int n8[7];
};

__global__ __launch_bounds__(256) void cvt_bf16(CvtArgs c) {
    const int z = blockIdx.z;
    const int i = blockIdx.x * 256 + threadIdx.x;
    if (i >= c.n8[z]) return;
    const float4* s = (const float4*)c.src[z];
    const float4 a = s[2 * i];
    const float4 b = s[2 * i + 1];
    union { short8 v; u16 u[8]; } o;
    o.u[0] = f2bf(a.x); o.u[1] = f2bf(a.y); o.u[2] = f2bf(a.z); o.u[3] = f2bf(a.w);
    o.u[4] = f2bf(b.x); o.u[5] = f2bf(b.y); o.u[6] = f2bf(b.z); o.u[7] = f2bf(b.w);
    ((short8*)c.dst[z])[i] = o.v;
}

// ---------------------------------------------------------------------------
// bf16 MFMA GEMM: normal mode:   C[M,N] = (A @ W^T + bias) * scale
//                 trans mode(z): C^T into [b][dim][t] layout, i.e. pass
//                 A=weights, W=activations; D[row=dim][col=token];
//                 store at (token>>11)*2097152 + dim*2048 + (token&2047).
// m97-style: 128x128 tile, BK=32, 4 waves, global_load_lds staging.
// ---------------------------------------------------------------------------
struct GemmArgs {
    const u16* A[3];
    const u16* W[3];
    const float* bias[3];
    void* C[3];
    float scale[3];
    int trans[3];
};

template <bool BF16OUT>
__global__ __launch_bounds__(256) void gemm_nt_mfma(GemmArgs ga, int M, int N, int K)
{
    __shared__ u16 As[128 * 32];
    __shared__ u16 Bs[128 * 32];
    const int z = blockIdx.z;
    const u16* __restrict__ A = ga.A[z];
    const u16* __restrict__ W = ga.W[z];
    const float* __restrict__ bias = ga.bias[z];
    const float scale = ga.scale[z];
    const int trans = ga.trans[z];

    const int tid = threadIdx.x;
    const int w = tid >> 6, l = tid & 63;
    const int l4 = l >> 4, lm = l & 15;
    const int wr = w >> 1, wc = w & 1;
    const int bm = (trans ? blockIdx.x : blockIdx.y) * 128;
    const int bn = (trans ? blockIdx.y : blockIdx.x) * 128;

    const int srow = l >> 2;
    const int sseg = l & 3;

    f32x4 acc[4][4];
#pragma unroll
    for (int m = 0; m < 4; ++m)
#pragma unroll
        for (int n = 0; n < 4; ++n) acc[m][n] = (f32x4){0.f, 0.f, 0.f, 0.f};

    for (int k0 = 0; k0 < K; k0 += 32) {
        __syncthreads();
#pragma unroll
        for (int i = 0; i < 2; ++i) {
            const int blk = w * 2 + i;
            const int row = blk * 16 + srow;
            load_lds16(A + (size_t)(bm + row) * K + k0 + sseg * 8,
                       (char*)As + blk * 1024);
            load_lds16(W + (size_t)(bn + row) * K + k0 + sseg * 8,
                       (char*)Bs + blk * 1024);
        }
        __syncthreads();

        short8 af[4], bf[4];
#pragma unroll
        for (int m = 0; m < 4; ++m)
            af[m] = *(const short8*)&As[(wr * 64 + m * 16 + lm) * 32 + l4 * 8];
#pragma unroll
        for (int n = 0; n < 4; ++n)
            bf[n] = *(const short8*)&Bs[(wc * 64 + n * 16 + lm) * 32 + l4 * 8];
#pragma unroll
        for (int m = 0; m < 4; ++m)
#pragma unroll
            for (int n = 0; n < 4; ++n)
                acc[m][n] = __builtin_amdgcn_mfma_f32_16x16x32_bf16(af[m], bf[n], acc[m][n], 0, 0, 0);
    }

    if (!trans) {
        float bv[4];
#pragma unroll
        for (int n = 0; n < 4; ++n) bv[n] = bias[bn + wc * 64 + n * 16 + lm];
#pragma unroll
        for (int m = 0; m < 4; ++m) {
#pragma unroll
            for (int n = 0; n < 4; ++n) {
                const int col = bn + wc * 64 + n * 16 + lm;
#pragma unroll
                for (int r = 0; r < 4; ++r) {
                    const int row = bm + wr * 64 + m * 16 + l4 * 4 + r;
                    const float v = (acc[m][n][r] + bv[n]) * scale;
                    if (BF16OUT)
                        ((u16*)ga.C[z])[(size_t)row * N + col] = f2bf(v);
                    else
                        ((float*)ga.C[z])[(size_t)row * N + col] = v;
                }
            }
        }
    } else {
        // transposed output: row = dim, col = token; bias indexed by row
#pragma unroll
        for (int m = 0; m < 4; ++m) {
            const float4 bv4 = *(const float4*)(bias + bm + wr * 64 + m * 16 + l4 * 4);
            const float bvr[4] = {bv4.x, bv4.y, bv4.z, bv4.w};
#pragma unroll
            for (int n = 0; n < 4; ++n) {
                const int col = bn + wc * 64 + n * 16 + lm;            // token
                const size_t cbase = (size_t)(col >> 11) * 2097152 + (size_t)(col & 2047);
#pragma unroll
                for (int r = 0; r < 4; ++r) {
                    const int row = bm + wr * 64 + m * 16 + l4 * 4 + r; // dim
                    const float v = (acc[m][n][r] + bvr[r]) * scale;
                    ((u16*)ga.C[z])[cbase + (size_t)row * 2048] = f2bf(v);
                }
            }
        }
    }
}

// ---------------------------------------------------------------------------
// Flash attention v4: swapped QK^T (scores pre-scaled to log2 domain by the
// Q-projection epilogue), QBLK=128 (4 waves x 32 q), KVBLK=64.
// K staged [key][d-chunk ^ (key&7)] and V^T staged [d][key-chunk ^ (d&7)],
// both double-buffered via global_load_lds with pre-swizzled per-lane global
// sources (linear LDS dest). P roundtrips per-wave LDS (verified R4 path).
//
// mfma_f32_16x16x32_bf16 frags:
//   A: row=lane&15, k=(lane>>4)*8+j   B: col=lane&15, k=(lane>>4)*8+j
//   C/D: col=lane&15, row=(lane>>4)*4+reg   [HW-verified m89]
// QK^T: A=K, B=Q  ->  lane holds S[key=16g+4*l4+r][q=qa*16+lm]
// PV:   A=P, B=V^T -> lane holds O[q=qa*16+4*l4+r][d=16g+lm]
// ---------------------------------------------------------------------------
__global__ __launch_bounds__(256) void flash_attn_mfma4(
    const u16* __restrict__ Qb, const u16* __restrict__ Kb,
    const u16* __restrict__ Vt, u16* __restrict__ Ob)
{
    __shared__ u16 Ks[2][64 * 64];
    __shared__ u16 Vs[2][64 * 64];
    __shared__ u16 Ps[4][32 * 64];

    const int tid = threadIdx.x;
    const int w  = tid >> 6;
    const int l  = tid & 63;
    const int l4 = l >> 4;
    const int lm = l & 15;
    const int qb0 = blockIdx.x << 7;
    const int h  = blockIdx.y;
    const int b  = blockIdx.z;
    const size_t bbase = (size_t)b * 2048 * 1024 + (size_t)h * 64;       // [B,S,E]
    const size_t vbase = (size_t)b * 2097152 + (size_t)(h * 64) * 2048;  // [B,E,T]

    // Q fragments (B-operand): qf[qa][c], q = qb0 + w*32 + qa*16 + lm
    short8 qf[2][2];
#pragma unroll
    for (int qa = 0; qa < 2; ++qa) {
        const u16* qrow = Qb + bbase + (size_t)(qb0 + w * 32 + qa * 16 + lm) * 1024;
#pragma unroll
        for (int c = 0; c < 2; ++c)
            qf[qa][c] = *(const short8*)(qrow + c * 32 + l4 * 8);
    }

    auto stageK = [&](int t0, int bufi) {
#pragma unroll
        for (int ii = 0; ii < 2; ++ii) {
            const int i = w * 2 + ii;
            const int key = i * 8 + (l >> 3);
            const int chunk = (l & 7) ^ ((l >> 3) & 7);
            load_lds16(Kb + bbase + (size_t)(t0 + key) * 1024 + chunk * 8,
                       (char*)&Ks[bufi][0] + i * 1024);
        }
    };
    auto stageV = [&](int t0, int bufi) {
#pragma unroll
        for (int ii = 0; ii < 2; ++ii) {
            const int i = w * 2 + ii;
            const int d = i * 8 + (l >> 3);
            const int chunk = (l & 7) ^ ((l >> 3) & 7);   // == (l&7)^(d&7)
            load_lds16(Vt + vbase + (size_t)d * 2048 + t0 + chunk * 8,
                       (char*)&Vs[bufi][0] + i * 1024);
        }
    };

    f32x4 oacc[2][4];
#pragma unroll
    for (int qa = 0; qa < 2; ++qa)
#pragma unroll
        for (int g = 0; g < 4; ++g) oacc[qa][g] = (f32x4){0.f, 0.f, 0.f, 0.f};
    float m_run[2] = {-1e30f, -1e30f};
    float l_run[2] = {0.f, 0.f};

    stageK(0, 0);
    stageV(0, 0);
    __syncthreads();

    for (int t = 0; t < 32; ++t) {
        const int buf = t & 1;
        if (t < 31) {
            stageK((t + 1) * 64, buf ^ 1);
            stageV((t + 1) * 64, buf ^ 1);
        }

        // ---- QK^T (swapped): lane holds S[key=16g+4*l4+r][q=qa*16+lm] ----
        f32x4 sacc[2][4];
#pragma unroll
        for (int qa = 0; qa < 2; ++qa)
#pragma unroll
            for (int g = 0; g < 4; ++g) sacc[qa][g] = (f32x4){0.f, 0.f, 0.f, 0.f};
#pragma unroll
        for (int g = 0; g < 4; ++g) {
#pragma unroll
            for (int c = 0; c < 2; ++c) {
                const short8 kf = *(const short8*)
                    &Ks[buf][(16 * g + lm) * 64 + (((4 * c + l4) ^ (lm & 7)) << 3)];
                sacc[0][g] = __builtin_amdgcn_mfma_f32_16x16x32_bf16(kf, qf[0][c], sacc[0][g], 0, 0, 0);
                sacc[1][g] = __builtin_amdgcn_mfma_f32_16x16x32_bf16(kf, qf[1][c], sacc[1][g], 0, 0, 0);
            }
        }

        // ---- softmax in log2 domain (scores already x 0.125*log2e) ----
        float mt[2];
#pragma unroll
        for (int qa = 0; qa < 2; ++qa) {
            float a0 = fmaxf(fmaxf(sacc[qa][0][0], sacc[qa][0][1]), fmaxf(sacc[qa][0][2], sacc[qa][0][3]));
            float a1 = fmaxf(fmaxf(sacc[qa][1][0], sacc[qa][1][1]), fmaxf(sacc[qa][1][2], sacc[qa][1][3]));
            float a2 = fmaxf(fmaxf(sacc[qa][2][0], sacc[qa][2][1]), fmaxf(sacc[qa][2][2], sacc[qa][2][3]));
            float a3 = fmaxf(fmaxf(sacc[qa][3][0], sacc[qa][3][1]), fmaxf(sacc[qa][3][2], sacc[qa][3][3]));
            float m0 = fmaxf(fmaxf(a0, a1), fmaxf(a2, a3));
            m0 = fmaxf(m0, __shfl_xor(m0, 16));
            m0 = fmaxf(m0, __shfl_xor(m0, 32));
            mt[qa] = m0;
        }
        const bool resc = !__all((mt[0] <= m_run[0]) && (mt[1] <= m_run[1]));
        if (resc) {
            float alpha[2];
#pragma unroll
            for (int qa = 0; qa < 2; ++qa) {
                const float mn = fmaxf(m_run[qa], mt[qa]);
                alpha[qa] = __builtin_amdgcn_exp2f(m_run[qa] - mn);
                m_run[qa] = mn;
                l_run[qa] *= alpha[qa];
            }
#pragma unroll
            for (int qa = 0; qa < 2; ++qa)
#pragma unroll
                for (int r = 0; r < 4; ++r) {
                    const float a = __shfl(alpha[qa], l4 * 4 + r);
#pragma unroll
                    for (int g = 0; g < 4; ++g) oacc[qa][g][r] *= a;
                }
        }
#pragma unroll
        for (int qa = 0; qa < 2; ++qa) {
            float lsum = 0.f;
            const float mr = m_run[qa];
#pragma unroll
            for (int g = 0; g < 4; ++g) {
                const float p0 = __builtin_amdgcn_exp2f(sacc[qa][g][0] - mr);
                const float p1 = __builtin_amdgcn_exp2f(sacc[qa][g][1] - mr);
                const float p2 = __builtin_amdgcn_exp2f(sacc[qa][g][2] - mr);
                const float p3 = __builtin_amdgcn_exp2f(sacc[qa][g][3] - mr);
                lsum += (p0 + p1) + (p2 + p3);
                ushort4 pk;
                pk.x = f2bf(p0); pk.y = f2bf(p1); pk.z = f2bf(p2); pk.w = f2bf(p3);
                *(ushort4*)&Ps[w][(qa * 16 + lm) * 64 + (((g * 4 + l4) ^ ((lm & 7) << 1)) << 2)] = pk;
            }
            lsum += __shfl_xor(lsum, 16);
            lsum += __shfl_xor(lsum, 32);
            l_run[qa] += lsum;
        }

        // ---- PV: oacc[qa][g] += P_qa . V^T_g  (plain swizzled b128 reads) ----
#pragma unroll
        for (int c = 0; c < 2; ++c) {
            short8 pa[2];
#pragma unroll
            for (int qa = 0; qa < 2; ++qa)
                pa[qa] = *(const short8*)
                    &Ps[w][(qa * 16 + lm) * 64 + (((c * 8 + l4 * 2) ^ ((lm & 7) << 1)) << 2)];
#pragma unroll
            for (int g = 0; g < 4; ++g) {
                const short8 vf = *(const short8*)
                    &Vs[buf][(16 * g + lm) * 64 + (((4 * c + l4) ^ (lm & 7)) << 3)];
                oacc[0][g] = __builtin_amdgcn_mfma_f32_16x16x32_bf16(pa[0], vf, oacc[0][g], 0, 0, 0);
                oacc[1][g] = __builtin_amdgcn_mfma_f32_16x16x32_bf16(pa[1], vf, oacc[1][g], 0, 0, 0);
            }
        }

        __syncthreads();
    }

    // ---- epilogue ----
#pragma unroll
    for (int qa = 0; qa < 2; ++qa) {
#pragma unroll
        for (int r = 0; r < 4; ++r) {
            const float linv = 1.f / __shfl(l_run[qa], l4 * 4 + r);
            const size_t orow = bbase + (size_t)(qb0 + w * 32 + qa * 16 + l4 * 4 + r) * 1024;
#pragma unroll
            for (int g = 0; g < 4; ++g)
                Ob[orow + g * 16 + lm] = f2bf(oacc[qa][g][r] * linv);
        }
    }
}

extern "C" void kernel_launch(void* const* d_in, const int* in_sizes, int n_in,
                              void* d_out, int out_size, void* d_ws, size_t ws_size,
                              hipStream_t stream)
{
    const float* query = (const float*)d_in[0];
    const float* value = (const float*)d_in[1];
    const float* key   = (const float*)d_in[2];
    const float* Wq = (const float*)d_in[3];
    const float* bq = (const float*)d_in[4];
    const float* Wk = (const float*)d_in[5];
    const float* bk = (const float*)d_in[6];
    const float* Wv = (const float*)d_in[7];
    const float* bv = (const float*)d_in[8];
    const float* Wo = (const float*)d_in[9];
    const float* bo = (const float*)d_in[10];
    float* out = (float*)d_out;

    const int M = 2 * 2048;
    const int E = 1024;
    const size_t act = (size_t)M * E;
    const size_t wel = (size_t)E * E;

    u16* qc  = (u16*)d_ws;
    u16* kc  = qc + act;
    u16* vc  = kc + act;
    u16* wqb = vc + act;
    u16* wkb = wqb + wel;
    u16* wvb = wkb + wel;
    u16* wob = wvb + wel;
    u16* Qb  = wob + wel;
    u16* Kb  = Qb + act;
    u16* Vtb = Kb + act;   // V^T in [B, E, T] layout
    u16* Ab  = Vtb + act;

    CvtArgs ca;
    ca.src[0] = query; ca.dst[0] = qc;  ca.n8[0] = (int)(act / 8);
    ca.src[1] = key;   ca.dst[1] = kc;  ca.n8[1] = (int)(act / 8);
    ca.src[2] = value; ca.dst[2] = vc;  ca.n8[2] = (int)(act / 8);
    ca.src[3] = Wq;    ca.dst[3] = wqb; ca.n8[3] = (int)(wel / 8);
    ca.src[4] = Wk;    ca.dst[4] = wkb; ca.n8[4] = (int)(wel / 8);
    ca.src[5] = Wv;    ca.dst[5] = wvb; ca.n8[5] = (int)(wel / 8);
    ca.src[6] = Wo;    ca.dst[6] = wob; ca.n8[6] = (int)(wel / 8);
    dim3 cgrid((unsigned)((act / 8 + 255) / 256), 1, 7);
    hipLaunchKernelGGL(cvt_bf16, cgrid, dim3(256), 0, stream, ca);

    // q pre-scaled by (1/sqrt(D)) * log2(e): softmax runs on raw v_exp_f32
    const float SCALE_Q = 0.125f * 1.4426950408889634f;

    GemmArgs gq;
    gq.A[0] = qc;  gq.W[0] = wqb; gq.bias[0] = bq; gq.C[0] = Qb;  gq.scale[0] = SCALE_Q; gq.trans[0] = 0;
    gq.A[1] = kc;  gq.W[1] = wkb; gq.bias[1] = bk; gq.C[1] = Kb;  gq.scale[1] = 1.0f;    gq.trans[1] = 0;
    gq.A[2] = wvb; gq.W[2] = vc;  gq.bias[2] = bv; gq.C[2] = Vtb; gq.scale[2] = 1.0f;    gq.trans[2] = 1;
    dim3 ggrid(E / 128, M / 128, 3);
    hipLaunchKernelGGL((gemm_nt_mfma<true>), ggrid, dim3(256), 0, stream, gq, M, E, E);

    dim3 fgrid(2048 / 128, 16, 2);
    hipLaunchKernelGGL(flash_attn_mfma4, fgrid, dim3(256), 0, stream, Qb, Kb, Vtb, Ab);

    GemmArgs go;
    go.A[0] = Ab; go.W[0] = wob; go.bias[0] = bo; go.C[0] = out; go.scale[0] = 1.0f; go.trans[0] = 0;
    go.A[1] = Ab; go.W[1] = wob; go.bias[1] = bo; go.C[1] = out; go.scale[1] = 1.0f; go.trans[1] = 0;
    go.A[2] = Ab; go.W[2] = wob; go.bias[2] = bo; go.C[2] = out; go.scale[2] = 1.0f; go.trans[2] = 0;
    dim3 ogrid(E / 128, M / 128, 1);
    hipLaunchKernelGGL((gemm_nt_mfma<false>), ogrid, dim3(256), 0, stream, go, M, E, E);
}

// Round 7
// 161.465 us; speedup vs baseline: 1.0937x; 1.0937x over previous
//
#include <hip/hip_runtime.h>
#include <math.h>

// Problem constants: B=2, S=T=2048, E=1024, H=16, D=64
typedef __attribute__((ext_vector_type(8))) short short8;
typedef __attribute__((ext_vector_type(4))) float f32x4;
typedef unsigned short u16;

// fp32 -> bf16 round-to-nearest-even (finite inputs)
__device__ __forceinline__ u16 f2bf(float x) {
    unsigned int u = __float_as_uint(x);
    u += 0x7FFFu + ((u >> 16) & 1u);
    return (u16)(u >> 16);
}

// packed fp32x2 -> bf16x2 (RNE), single instruction; no builtin on gfx950
__device__ __forceinline__ unsigned cvt_pk_bf16(float lo, float hi) {
    unsigned r;
    asm("v_cvt_pk_bf16_f32 %0, %1, %2" : "=v"(r) : "v"(lo), "v"(hi));
    return r;
}

__device__ __forceinline__ void load_lds16(const void* g, void* l) {
    __builtin_amdgcn_global_load_lds(
        (const __attribute__((address_space(1))) unsigned int*)g,
        (__attribute__((address_space(3))) unsigned int*)l,
        16, 0, 0);
}

// ---------------------------------------------------------------------------
// Batched fp32 -> bf16 convert (7 tensors)
// ---------------------------------------------------------------------------
struct CvtArgs {
    const float* src[7];
    u16* dst[7];
    int n8[7];
};

__global__ __launch_bounds__(256) void cvt_bf16(CvtArgs c) {
    const int z = blockIdx.z;
    const int i = blockIdx.x * 256 + threadIdx.x;
    if (i >= c.n8[z]) return;
    const float4* s = (const float4*)c.src[z];
    const float4 a = s[2 * i];
    const float4 b = s[2 * i + 1];
    union { short8 v; u16 u[8]; } o;
    o.u[0] = f2bf(a.x); o.u[1] = f2bf(a.y); o.u[2] = f2bf(a.z); o.u[3] = f2bf(a.w);
    o.u[4] = f2bf(b.x); o.u[5] = f2bf(b.y); o.u[6] = f2bf(b.z); o.u[7] = f2bf(b.w);
    ((short8*)c.dst[z])[i] = o.v;
}

// ---------------------------------------------------------------------------
// bf16 MFMA GEMM: normal mode:   C[M,N] = (A @ W^T + bias) * scale
//                 trans mode(z): C^T into [b][dim][t] layout (A=weights,
//                 W=activations; D[row=dim][col=token]).
// m97-style: 128x128 tile, BK=32, 4 waves, global_load_lds staging.
// ---------------------------------------------------------------------------
struct GemmArgs {
    const u16* A[3];
    const u16* W[3];
    const float* bias[3];
    void* C[3];
    float scale[3];
    int trans[3];
};

template <bool BF16OUT>
__global__ __launch_bounds__(256) void gemm_nt_mfma(GemmArgs ga, int M, int N, int K)
{
    __shared__ u16 As[128 * 32];
    __shared__ u16 Bs[128 * 32];
    const int z = blockIdx.z;
    const u16* __restrict__ A = ga.A[z];
    const u16* __restrict__ W = ga.W[z];
    const float* __restrict__ bias = ga.bias[z];
    const float scale = ga.scale[z];
    const int trans = ga.trans[z];

    const int tid = threadIdx.x;
    const int w = tid >> 6, l = tid & 63;
    const int l4 = l >> 4, lm = l & 15;
    const int wr = w >> 1, wc = w & 1;
    const int bm = (trans ? blockIdx.x : blockIdx.y) * 128;
    const int bn = (trans ? blockIdx.y : blockIdx.x) * 128;

    const int srow = l >> 2;
    const int sseg = l & 3;

    f32x4 acc[4][4];
#pragma unroll
    for (int m = 0; m < 4; ++m)
#pragma unroll
        for (int n = 0; n < 4; ++n) acc[m][n] = (f32x4){0.f, 0.f, 0.f, 0.f};

    for (int k0 = 0; k0 < K; k0 += 32) {
        __syncthreads();
#pragma unroll
        for (int i = 0; i < 2; ++i) {
            const int blk = w * 2 + i;
            const int row = blk * 16 + srow;
            load_lds16(A + (size_t)(bm + row) * K + k0 + sseg * 8,
                       (char*)As + blk * 1024);
            load_lds16(W + (size_t)(bn + row) * K + k0 + sseg * 8,
                       (char*)Bs + blk * 1024);
        }
        __syncthreads();

        short8 af[4], bf[4];
#pragma unroll
        for (int m = 0; m < 4; ++m)
            af[m] = *(const short8*)&As[(wr * 64 + m * 16 + lm) * 32 + l4 * 8];
#pragma unroll
        for (int n = 0; n < 4; ++n)
            bf[n] = *(const short8*)&Bs[(wc * 64 + n * 16 + lm) * 32 + l4 * 8];
#pragma unroll
        for (int m = 0; m < 4; ++m)
#pragma unroll
            for (int n = 0; n < 4; ++n)
                acc[m][n] = __builtin_amdgcn_mfma_f32_16x16x32_bf16(af[m], bf[n], acc[m][n], 0, 0, 0);
    }

    if (!trans) {
        float bv[4];
#pragma unroll
        for (int n = 0; n < 4; ++n) bv[n] = bias[bn + wc * 64 + n * 16 + lm];
#pragma unroll
        for (int m = 0; m < 4; ++m) {
#pragma unroll
            for (int n = 0; n < 4; ++n) {
                const int col = bn + wc * 64 + n * 16 + lm;
#pragma unroll
                for (int r = 0; r < 4; ++r) {
                    const int row = bm + wr * 64 + m * 16 + l4 * 4 + r;
                    const float v = (acc[m][n][r] + bv[n]) * scale;
                    if (BF16OUT)
                        ((u16*)ga.C[z])[(size_t)row * N + col] = f2bf(v);
                    else
                        ((float*)ga.C[z])[(size_t)row * N + col] = v;
                }
            }
        }
    } else {
#pragma unroll
        for (int m = 0; m < 4; ++m) {
            const float4 bv4 = *(const float4*)(bias + bm + wr * 64 + m * 16 + l4 * 4);
            const float bvr[4] = {bv4.x, bv4.y, bv4.z, bv4.w};
#pragma unroll
            for (int n = 0; n < 4; ++n) {
                const int col = bn + wc * 64 + n * 16 + lm;            // token
                const size_t cbase = (size_t)(col >> 11) * 2097152 + (size_t)(col & 2047);
#pragma unroll
                for (int r = 0; r < 4; ++r) {
                    const int row = bm + wr * 64 + m * 16 + l4 * 4 + r; // dim
                    const float v = (acc[m][n][r] + bvr[r]) * scale;
                    ((u16*)ga.C[z])[cbase + (size_t)row * 2048] = f2bf(v);
                }
            }
        }
    }
}

// ---------------------------------------------------------------------------
// Flash attention v5: 8 waves (512 thr), QBLK=128 (16 q/wave), KVBLK=64.
// Swapped QK^T in exp2 domain (Q pre-scaled by 0.125*log2e). K and V^T both
// double-buffered via global_load_lds with pre-swizzled per-lane sources.
// P packed with v_cvt_pk_bf16_f32, roundtripped through per-wave LDS (b64).
//
// mfma_f32_16x16x32_bf16 frags:
//   A: row=lane&15, k=(lane>>4)*8+j   B: col=lane&15, k=(lane>>4)*8+j
//   C/D: col=lane&15, row=(lane>>4)*4+reg   [HW-verified m89]
// QK^T: A=K, B=Q   -> lane holds S[key=16g+4*l4+r][q=lm]
// PV:   A=P, B=V^T -> lane holds O[q=4*l4+r][d=16g+lm]
// ---------------------------------------------------------------------------
__global__ __launch_bounds__(512, 4) void flash_attn_mfma5(
    const u16* __restrict__ Qb, const u16* __restrict__ Kb,
    const u16* __restrict__ Vt, u16* __restrict__ Ob)
{
    __shared__ u16 Ks[2][64 * 64];
    __shared__ u16 Vs[2][64 * 64];
    __shared__ u16 Ps[8][16 * 64];

    const int tid = threadIdx.x;
    const int w  = tid >> 6;     // 0..7
    const int l  = tid & 63;
    const int l4 = l >> 4;
    const int lm = l & 15;
    const int qb0 = blockIdx.x << 7;
    const int h  = blockIdx.y;
    const int b  = blockIdx.z;
    const size_t bbase = (size_t)b * 2048 * 1024 + (size_t)h * 64;       // [B,S,E]
    const size_t vbase = (size_t)b * 2097152 + (size_t)(h * 64) * 2048;  // [B,E,T]

    // Q fragments (B-operand): q = qb0 + w*16 + lm
    short8 qf[2];
    {
        const u16* qrow = Qb + bbase + (size_t)(qb0 + w * 16 + lm) * 1024;
        qf[0] = *(const short8*)(qrow + l4 * 8);
        qf[1] = *(const short8*)(qrow + 32 + l4 * 8);
    }

    // staging: wave w covers rows w*8 .. w*8+7 of the 64x64 tile, 1 issue/thread
    auto stageK = [&](int t0, int bufi) {
        const int key = w * 8 + (l >> 3);
        const int chunk = (l & 7) ^ ((l >> 3) & 7);
        load_lds16(Kb + bbase + (size_t)(t0 + key) * 1024 + chunk * 8,
                   (char*)&Ks[bufi][0] + w * 1024);
    };
    auto stageV = [&](int t0, int bufi) {
        const int d = w * 8 + (l >> 3);
        const int chunk = (l & 7) ^ ((l >> 3) & 7);
        load_lds16(Vt + vbase + (size_t)d * 2048 + t0 + chunk * 8,
                   (char*)&Vs[bufi][0] + w * 1024);
    };

    f32x4 oacc[4];
#pragma unroll
    for (int g = 0; g < 4; ++g) oacc[g] = (f32x4){0.f, 0.f, 0.f, 0.f};
    float m_run = -1e30f;
    float l_run = 0.f;

    stageK(0, 0);
    stageV(0, 0);
    __syncthreads();

    for (int t = 0; t < 32; ++t) {
        const int buf = t & 1;
        if (t < 31) {
            stageK((t + 1) * 64, buf ^ 1);
            stageV((t + 1) * 64, buf ^ 1);
        }

        // ---- QK^T (swapped): lane holds S[key=16g+4*l4+r][q=lm] ----
        f32x4 sacc[4];
#pragma unroll
        for (int g = 0; g < 4; ++g) sacc[g] = (f32x4){0.f, 0.f, 0.f, 0.f};
#pragma unroll
        for (int g = 0; g < 4; ++g) {
#pragma unroll
            for (int c = 0; c < 2; ++c) {
                const short8 kf = *(const short8*)
                    &Ks[buf][(16 * g + lm) * 64 + (((4 * c + l4) ^ (lm & 7)) << 3)];
                sacc[g] = __builtin_amdgcn_mfma_f32_16x16x32_bf16(kf, qf[c], sacc[g], 0, 0, 0);
            }
        }

        // ---- softmax in log2 domain; 16 scores in-lane + 2 shfl ----
        float a0 = fmaxf(fmaxf(sacc[0][0], sacc[0][1]), fmaxf(sacc[0][2], sacc[0][3]));
        float a1 = fmaxf(fmaxf(sacc[1][0], sacc[1][1]), fmaxf(sacc[1][2], sacc[1][3]));
        float a2 = fmaxf(fmaxf(sacc[2][0], sacc[2][1]), fmaxf(sacc[2][2], sacc[2][3]));
        float a3 = fmaxf(fmaxf(sacc[3][0], sacc[3][1]), fmaxf(sacc[3][2], sacc[3][3]));
        float mt = fmaxf(fmaxf(a0, a1), fmaxf(a2, a3));
        mt = fmaxf(mt, __shfl_xor(mt, 16));
        mt = fmaxf(mt, __shfl_xor(mt, 32));

        const bool resc = !__all(mt <= m_run);
        if (resc) {
            const float mn = fmaxf(m_run, mt);
            const float alpha = __builtin_amdgcn_exp2f(m_run - mn);
            m_run = mn;
            l_run *= alpha;
#pragma unroll
            for (int r = 0; r < 4; ++r) {
                const float a = __shfl(alpha, l4 * 4 + r);
#pragma unroll
                for (int g = 0; g < 4; ++g) oacc[g][r] *= a;
            }
        }

        float lsum = 0.f;
        const float mr = m_run;
#pragma unroll
        for (int g = 0; g < 4; ++g) {
            const float p0 = __builtin_amdgcn_exp2f(sacc[g][0] - mr);
            const float p1 = __builtin_amdgcn_exp2f(sacc[g][1] - mr);
            const float p2 = __builtin_amdgcn_exp2f(sacc[g][2] - mr);
            const float p3 = __builtin_amdgcn_exp2f(sacc[g][3] - mr);
            lsum += (p0 + p1) + (p2 + p3);
            uint2 pk;
            pk.x = cvt_pk_bf16(p0, p1);
            pk.y = cvt_pk_bf16(p2, p3);
            *(uint2*)&Ps[w][lm * 64 + (((g * 4 + l4) ^ ((lm & 7) << 1)) << 2)] = pk;
        }
        lsum += __shfl_xor(lsum, 16);
        lsum += __shfl_xor(lsum, 32);
        l_run += lsum;

        // ---- PV: oacc[g] += P . V^T_g ----
#pragma unroll
        for (int c = 0; c < 2; ++c) {
            const short8 pa = *(const short8*)
                &Ps[w][lm * 64 + (((c * 8 + l4 * 2) ^ ((lm & 7) << 1)) << 2)];
#pragma unroll
            for (int g = 0; g < 4; ++g) {
                const short8 vf = *(const short8*)
                    &Vs[buf][(16 * g + lm) * 64 + (((4 * c + l4) ^ (lm & 7)) << 3)];
                oacc[g] = __builtin_amdgcn_mfma_f32_16x16x32_bf16(pa, vf, oacc[g], 0, 0, 0);
            }
        }

        __syncthreads();
    }

    // ---- epilogue ----
#pragma unroll
    for (int r = 0; r < 4; ++r) {
        const float linv = 1.f / __shfl(l_run, l4 * 4 + r);
        const size_t orow = bbase + (size_t)(qb0 + w * 16 + l4 * 4 + r) * 1024;
#pragma unroll
        for (int g = 0; g < 4; ++g)
            Ob[orow + g * 16 + lm] = f2bf(oacc[g][r] * linv);
    }
}

extern "C" void kernel_launch(void* const* d_in, const int* in_sizes, int n_in,
                              void* d_out, int out_size, void* d_ws, size_t ws_size,
                              hipStream_t stream)
{
    const float* query = (const float*)d_in[0];
    const float* value = (const float*)d_in[1];
    const float* key   = (const float*)d_in[2];
    const float* Wq = (const float*)d_in[3];
    const float* bq = (const float*)d_in[4];
    const float* Wk = (const float*)d_in[5];
    const float* bk = (const float*)d_in[6];
    const float* Wv = (const float*)d_in[7];
    const float* bv = (const float*)d_in[8];
    const float* Wo = (const float*)d_in[9];
    const float* bo = (const float*)d_in[10];
    float* out = (float*)d_out;

    const int M = 2 * 2048;
    const int E = 1024;
    const size_t act = (size_t)M * E;
    const size_t wel = (size_t)E * E;

    u16* qc  = (u16*)d_ws;
    u16* kc  = qc + act;
    u16* vc  = kc + act;
    u16* wqb = vc + act;
    u16* wkb = wqb + wel;
    u16* wvb = wkb + wel;
    u16* wob = wvb + wel;
    u16* Qb  = wob + wel;
    u16* Kb  = Qb + act;
    u16* Vtb = Kb + act;   // V^T in [B, E, T] layout
    u16* Ab  = Vtb + act;

    CvtArgs ca;
    ca.src[0] = query; ca.dst[0] = qc;  ca.n8[0] = (int)(act / 8);
    ca.src[1] = key;   ca.dst[1] = kc;  ca.n8[1] = (int)(act / 8);
    ca.src[2] = value; ca.dst[2] = vc;  ca.n8[2] = (int)(act / 8);
    ca.src[3] = Wq;    ca.dst[3] = wqb; ca.n8[3] = (int)(wel / 8);
    ca.src[4] = Wk;    ca.dst[4] = wkb; ca.n8[4] = (int)(wel / 8);
    ca.src[5] = Wv;    ca.dst[5] = wvb; ca.n8[5] = (int)(wel / 8);
    ca.src[6] = Wo;    ca.dst[6] = wob; ca.n8[6] = (int)(wel / 8);
    dim3 cgrid((unsigned)((act / 8 + 255) / 256), 1, 7);
    hipLaunchKernelGGL(cvt_bf16, cgrid, dim3(256), 0, stream, ca);

    // q pre-scaled by (1/sqrt(D)) * log2(e): softmax runs on raw v_exp_f32
    const float SCALE_Q = 0.125f * 1.4426950408889634f;

    GemmArgs gq;
    gq.A[0] = qc;  gq.W[0] = wqb; gq.bias[0] = bq; gq.C[0] = Qb;  gq.scale[0] = SCALE_Q; gq.trans[0] = 0;
    gq.A[1] = kc;  gq.W[1] = wkb; gq.bias[1] = bk; gq.C[1] = Kb;  gq.scale[1] = 1.0f;    gq.trans[1] = 0;
    gq.A[2] = wvb; gq.W[2] = vc;  gq.bias[2] = bv; gq.C[2] = Vtb; gq.scale[2] = 1.0f;    gq.trans[2] = 1;
    dim3 ggrid(E / 128, M / 128, 3);
    hipLaunchKernelGGL((gemm_nt_mfma<true>), ggrid, dim3(256), 0, stream, gq, M, E, E);

    dim3 fgrid(2048 / 128, 16, 2);
    hipLaunchKernelGGL(flash_attn_mfma5, fgrid, dim3(512), 0, stream, Qb, Kb, Vtb, Ab);

    GemmArgs go;
    go.A[0] = Ab; go.W[0] = wob; go.bias[0] = bo; go.C[0] = out; go.scale[0] = 1.0f; go.trans[0] = 0;
    go.A[1] = Ab; go.W[1] = wob; go.bias[1] = bo; go.C[1] = out; go.scale[1] = 1.0f; go.trans[1] = 0;
    go.A[2] = Ab; go.W[2] = wob; go.bias[2] = bo; go.C[2] = out; go.scale[2] = 1.0f; go.trans[2] = 0;
    dim3 ogrid(E / 128, M / 128, 1);
    hipLaunchKernelGGL((gemm_nt_mfma<false>), ogrid, dim3(256), 0, stream, go, M, E, E);
}

// Round 8
// 154.800 us; speedup vs baseline: 1.1408x; 1.0431x over previous
//
#include <hip/hip_runtime.h>
#include <math.h>

// Problem constants: B=2, S=T=2048, E=1024, H=16, D=64
typedef __attribute__((ext_vector_type(8))) short short8;
typedef __attribute__((ext_vector_type(4))) float f32x4;
typedef unsigned short u16;

// fp32 -> bf16 round-to-nearest-even (finite inputs)
__device__ __forceinline__ u16 f2bf(float x) {
    unsigned int u = __float_as_uint(x);
    u += 0x7FFFu + ((u >> 16) & 1u);
    return (u16)(u >> 16);
}

// packed fp32x2 -> bf16x2, single instruction; no builtin on gfx950
__device__ __forceinline__ unsigned cvt_pk_bf16(float lo, float hi) {
    unsigned r;
    asm("v_cvt_pk_bf16_f32 %0, %1, %2" : "=v"(r) : "v"(lo), "v"(hi));
    return r;
}

__device__ __forceinline__ void load_lds16(const void* g, void* l) {
    __builtin_amdgcn_global_load_lds(
        (const __attribute__((address_space(1))) unsigned int*)g,
        (__attribute__((address_space(3))) unsigned int*)l,
        16, 0, 0);
}

// ---------------------------------------------------------------------------
// bf16 MFMA GEMM with fused fp32->bf16 staging.
//   A_FP32=true : A is fp32, reg-staged + cvt_pk (query/key/Wv paths)
//   A_FP32=false: A is bf16, global_load_lds staged (Wo path, A=attn out)
//   W is ALWAYS fp32, reg-staged + cvt_pk.
//   normal: C[M,N] = (A @ W^T + bias)*scale ; trans: C^T into [b][dim][tok].
// 128x128 tile, BK=32, 4 waves; next-tile loads issued after barrier2 (T14).
// ---------------------------------------------------------------------------
struct GemmArgs {
    const void* A[3];
    const float* W[3];
    const float* bias[3];
    void* C[3];
    float scale[3];
    int trans[3];
};

template <bool A_FP32, bool BF16OUT>
__global__ __launch_bounds__(256) void gemm_nt_mfma(GemmArgs ga, int M, int N, int K)
{
    __shared__ u16 As[128 * 32];
    __shared__ u16 Bs[128 * 32];
    const int z = blockIdx.z;
    const float* __restrict__ Wf = ga.W[z];
    const float* __restrict__ bias = ga.bias[z];
    const float scale = ga.scale[z];
    const int trans = ga.trans[z];
    const float* __restrict__ Af32 = (const float*)ga.A[z];
    const u16* __restrict__ Ab16 = (const u16*)ga.A[z];

    const int tid = threadIdx.x;
    const int w = tid >> 6, l = tid & 63;
    const int l4 = l >> 4, lm = l & 15;
    const int wr = w >> 1, wc = w & 1;
    const int bm = (trans ? blockIdx.x : blockIdx.y) * 128;
    const int bn = (trans ? blockIdx.y : blockIdx.x) * 128;

    // fp32 reg-staging geometry: j-th chunk row = tid>>2 + j*64, cols c8..c8+7
    const int r0 = tid >> 2;
    const int c8 = (tid & 3) * 8;
    // bf16 gload_lds geometry
    const int srow = l >> 2;
    const int sseg = l & 3;

    f32x4 acc[4][4];
#pragma unroll
    for (int m = 0; m < 4; ++m)
#pragma unroll
        for (int n = 0; n < 4; ++n) acc[m][n] = (f32x4){0.f, 0.f, 0.f, 0.f};

    float4 aR[2][2], wR[2][2];
    // prologue loads (tile 0)
#pragma unroll
    for (int j = 0; j < 2; ++j) {
        const int row = r0 + j * 64;
        if (A_FP32) {
            const float* p = Af32 + (size_t)(bm + row) * K + c8;
            aR[j][0] = *(const float4*)p;
            aR[j][1] = *(const float4*)(p + 4);
        }
        const float* q = Wf + (size_t)(bn + row) * K + c8;
        wR[j][0] = *(const float4*)q;
        wR[j][1] = *(const float4*)(q + 4);
    }

    for (int k0 = 0; k0 < K; k0 += 32) {
        __syncthreads();   // LDS consumers of previous tile done
        if (A_FP32) {
#pragma unroll
            for (int j = 0; j < 2; ++j) {
                const int row = r0 + j * 64;
                union { short8 v; unsigned u[4]; } o;
                o.u[0] = cvt_pk_bf16(aR[j][0].x, aR[j][0].y);
                o.u[1] = cvt_pk_bf16(aR[j][0].z, aR[j][0].w);
                o.u[2] = cvt_pk_bf16(aR[j][1].x, aR[j][1].y);
                o.u[3] = cvt_pk_bf16(aR[j][1].z, aR[j][1].w);
                *(short8*)&As[row * 32 + c8] = o.v;
            }
        } else {
#pragma unroll
            for (int i = 0; i < 2; ++i) {
                const int blk = w * 2 + i;
                const int row = blk * 16 + srow;
                load_lds16(Ab16 + (size_t)(bm + row) * K + k0 + sseg * 8,
                           (char*)As + blk * 1024);
            }
        }
#pragma unroll
        for (int j = 0; j < 2; ++j) {
            const int row = r0 + j * 64;
            union { short8 v; unsigned u[4]; } o;
            o.u[0] = cvt_pk_bf16(wR[j][0].x, wR[j][0].y);
            o.u[1] = cvt_pk_bf16(wR[j][0].z, wR[j][0].w);
            o.u[2] = cvt_pk_bf16(wR[j][1].x, wR[j][1].y);
            o.u[3] = cvt_pk_bf16(wR[j][1].z, wR[j][1].w);
            *(short8*)&Bs[row * 32 + c8] = o.v;
        }
        __syncthreads();   // staging visible (also drains gload_lds)

        const int k1 = k0 + 32;
        if (k1 < K) {      // issue next-tile loads early; hidden under MFMA
#pragma unroll
            for (int j = 0; j < 2; ++j) {
                const int row = r0 + j * 64;
                if (A_FP32) {
                    const float* p = Af32 + (size_t)(bm + row) * K + k1 + c8;
                    aR[j][0] = *(const float4*)p;
                    aR[j][1] = *(const float4*)(p + 4);
                }
                const float* q = Wf + (size_t)(bn + row) * K + k1 + c8;
                wR[j][0] = *(const float4*)q;
                wR[j][1] = *(const float4*)(q + 4);
            }
        }

        short8 af[4], bf[4];
#pragma unroll
        for (int m = 0; m < 4; ++m)
            af[m] = *(const short8*)&As[(wr * 64 + m * 16 + lm) * 32 + l4 * 8];
#pragma unroll
        for (int n = 0; n < 4; ++n)
            bf[n] = *(const short8*)&Bs[(wc * 64 + n * 16 + lm) * 32 + l4 * 8];
        __builtin_amdgcn_s_setprio(1);
#pragma unroll
        for (int m = 0; m < 4; ++m)
#pragma unroll
            for (int n = 0; n < 4; ++n)
                acc[m][n] = __builtin_amdgcn_mfma_f32_16x16x32_bf16(af[m], bf[n], acc[m][n], 0, 0, 0);
        __builtin_amdgcn_s_setprio(0);
    }

    if (!trans) {
        float bv[4];
#pragma unroll
        for (int n = 0; n < 4; ++n) bv[n] = bias[bn + wc * 64 + n * 16 + lm];
#pragma unroll
        for (int m = 0; m < 4; ++m) {
#pragma unroll
            for (int n = 0; n < 4; ++n) {
                const int col = bn + wc * 64 + n * 16 + lm;
#pragma unroll
                for (int r = 0; r < 4; ++r) {
                    const int row = bm + wr * 64 + m * 16 + l4 * 4 + r;
                    const float v = (acc[m][n][r] + bv[n]) * scale;
                    if (BF16OUT)
                        ((u16*)ga.C[z])[(size_t)row * N + col] = f2bf(v);
                    else
                        ((float*)ga.C[z])[(size_t)row * N + col] = v;
                }
            }
        }
    } else {
#pragma unroll
        for (int m = 0; m < 4; ++m) {
            const float4 bv4 = *(const float4*)(bias + bm + wr * 64 + m * 16 + l4 * 4);
            const float bvr[4] = {bv4.x, bv4.y, bv4.z, bv4.w};
#pragma unroll
            for (int n = 0; n < 4; ++n) {
                const int col = bn + wc * 64 + n * 16 + lm;            // token
                const size_t cbase = (size_t)(col >> 11) * 2097152 + (size_t)(col & 2047);
#pragma unroll
                for (int r = 0; r < 4; ++r) {
                    const int row = bm + wr * 64 + m * 16 + l4 * 4 + r; // dim
                    const float v = (acc[m][n][r] + bvr[r]) * scale;
                    ((u16*)ga.C[z])[cbase + (size_t)row * 2048] = f2bf(v);
                }
            }
        }
    }
}

// ---------------------------------------------------------------------------
// Flash attention v6: 8 waves (512 thr), QBLK=128 (16 q/wave), KVBLK=128
// (16 iters, 1 barrier each). Swapped QK^T in exp2 domain (Q pre-scaled by
// 0.125*log2e). K[128 keys][64 d] and V^T[64 d][128 keys] double-buffered via
// global_load_lds with pre-swizzled per-lane sources. PV split into two
// 64-key halves reusing a 64-wide per-wave P buffer. setprio around MFMA.
// Grid is 1D with bijective XCD decode: id = slot*8+xcd; each XCD owns 4
// (b,h) groups -> K/V panels L2-resident per XCD.
//
// frags: A: row=lane&15,k=(lane>>4)*8+j  B: col=lane&15,k=same
//        C/D: col=lane&15, row=(lane>>4)*4+reg  [HW-verified m89]
// ---------------------------------------------------------------------------
__global__ __launch_bounds__(512, 4) void flash_attn_mfma6(
    const u16* __restrict__ Qb, const u16* __restrict__ Kb,
    const u16* __restrict__ Vt, u16* __restrict__ Ob)
{
    __shared__ u16 Ks[2][128 * 64];   // [key][d-chunk ^ (key&7)]
    __shared__ u16 Vs[2][64 * 128];   // [d][key-chunk ^ (d&7)], chunk 4-bit
    __shared__ u16 Ps[8][16 * 64];    // per-wave [q][key-chunk4 ^ (2*(q&7))]

    const int tid = threadIdx.x;
    const int w  = tid >> 6;     // 0..7
    const int l  = tid & 63;
    const int l4 = l >> 4;
    const int lm = l & 15;

    // XCD-aware decode: id = slot*8 + xcd; slot = ghigh*16 + qtile
    const int id = blockIdx.x;
    const int xcd = id & 7;
    const int s = id >> 3;
    const int qt = s & 15;
    const int g0 = (s >> 4) * 8 + xcd;   // 0..31 = (b,h) group
    const int h = g0 & 15;
    const int b = g0 >> 4;
    const int qb0 = qt << 7;

    const size_t bbase = (size_t)b * 2048 * 1024 + (size_t)h * 64;       // [B,S,E]
    const size_t vbase = (size_t)b * 2097152 + (size_t)(h * 64) * 2048;  // [B,E,T]

    // Q fragments (B-operand): q = qb0 + w*16 + lm
    short8 qf[2];
    {
        const u16* qrow = Qb + bbase + (size_t)(qb0 + w * 16 + lm) * 1024;
        qf[0] = *(const short8*)(qrow + l4 * 8);
        qf[1] = *(const short8*)(qrow + 32 + l4 * 8);
    }

    auto stageK = [&](int t0, int bufi) {
#pragma unroll
        for (int ii = 0; ii < 2; ++ii) {
            const int i = w * 2 + ii;                 // 0..15
            const int key = i * 8 + (l >> 3);         // 0..127
            const int chunk = (l & 7) ^ ((l >> 3) & 7);
            load_lds16(Kb + bbase + (size_t)(t0 + key) * 1024 + chunk * 8,
                       (char*)&Ks[bufi][0] + i * 1024);
        }
    };
    auto stageV = [&](int t0, int bufi) {
#pragma unroll
        for (int ii = 0; ii < 2; ++ii) {
            const int i = w * 2 + ii;                 // 0..15
            const int d = i * 4 + (l >> 4);           // 0..63
            const int chunk = (l & 15) ^ (d & 7);     // 4-bit key-chunk
            load_lds16(Vt + vbase + (size_t)d * 2048 + t0 + chunk * 8,
                       (char*)&Vs[bufi][0] + i * 1024);
        }
    };

    f32x4 oacc[4];
#pragma unroll
    for (int g = 0; g < 4; ++g) oacc[g] = (f32x4){0.f, 0.f, 0.f, 0.f};
    float m_run = -1e30f;
    float l_run = 0.f;

    stageK(0, 0);
    stageV(0, 0);
    __syncthreads();

    for (int t = 0; t < 16; ++t) {
        const int buf = t & 1;
        if (t < 15) {
            stageK((t + 1) * 128, buf ^ 1);
            stageV((t + 1) * 128, buf ^ 1);
        }

        // ---- QK^T (swapped): lane holds S[key=16g+4*l4+r][q=lm] ----
        f32x4 sacc[8];
#pragma unroll
        for (int g = 0; g < 8; ++g) sacc[g] = (f32x4){0.f, 0.f, 0.f, 0.f};
        __builtin_amdgcn_s_setprio(1);
#pragma unroll
        for (int g = 0; g < 8; ++g) {
#pragma unroll
            for (int c = 0; c < 2; ++c) {
                const short8 kf = *(const short8*)
                    &Ks[buf][(16 * g + lm) * 64 + (((4 * c + l4) ^ (lm & 7)) << 3)];
                sacc[g] = __builtin_amdgcn_mfma_f32_16x16x32_bf16(kf, qf[c], sacc[g], 0, 0, 0);
            }
        }
        __builtin_amdgcn_s_setprio(0);

        // ---- softmax (log2 domain): 32 in-lane scores + 2 shfl ----
        float amax[8];
#pragma unroll
        for (int g = 0; g < 8; ++g)
            amax[g] = fmaxf(fmaxf(sacc[g][0], sacc[g][1]), fmaxf(sacc[g][2], sacc[g][3]));
        float mt = fmaxf(fmaxf(fmaxf(amax[0], amax[1]), fmaxf(amax[2], amax[3])),
                         fmaxf(fmaxf(amax[4], amax[5]), fmaxf(amax[6], amax[7])));
        mt = fmaxf(mt, __shfl_xor(mt, 16));
        mt = fmaxf(mt, __shfl_xor(mt, 32));

        const bool resc = !__all(mt <= m_run);
        if (resc) {
            const float mn = fmaxf(m_run, mt);
            const float alpha = __builtin_amdgcn_exp2f(m_run - mn);
            m_run = mn;
            l_run *= alpha;
#pragma unroll
            for (int r = 0; r < 4; ++r) {
                const float a = __shfl(alpha, l4 * 4 + r);
#pragma unroll
                for (int g = 0; g < 4; ++g) oacc[g][r] *= a;
            }
        }

        float lsum = 0.f;
        const float mr = m_run;
#pragma unroll
        for (int hh = 0; hh < 2; ++hh) {
            // P for this 64-key half
#pragma unroll
            for (int gg = 0; gg < 4; ++gg) {
                const int g = hh * 4 + gg;
                const float p0 = __builtin_amdgcn_exp2f(sacc[g][0] - mr);
                const float p1 = __builtin_amdgcn_exp2f(sacc[g][1] - mr);
                const float p2 = __builtin_amdgcn_exp2f(sacc[g][2] - mr);
                const float p3 = __builtin_amdgcn_exp2f(sacc[g][3] - mr);
                lsum += (p0 + p1) + (p2 + p3);
                uint2 pk;
                pk.x = cvt_pk_bf16(p0, p1);
                pk.y = cvt_pk_bf16(p2, p3);
                *(uint2*)&Ps[w][lm * 64 + (((gg * 4 + l4) ^ ((lm & 7) << 1)) << 2)] = pk;
            }
            // PV over this half
            __builtin_amdgcn_s_setprio(1);
#pragma unroll
            for (int c = 0; c < 2; ++c) {
                const short8 pa = *(const short8*)
                    &Ps[w][lm * 64 + (((c * 8 + l4 * 2) ^ ((lm & 7) << 1)) << 2)];
#pragma unroll
                for (int g = 0; g < 4; ++g) {
                    const int d = 16 * g + lm;
                    const short8 vf = *(const short8*)
                        &Vs[buf][d * 128 + (((hh * 8 + c * 4 + l4) ^ (d & 7)) << 3)];
                    oacc[g] = __builtin_amdgcn_mfma_f32_16x16x32_bf16(pa, vf, oacc[g], 0, 0, 0);
                }
            }
            __builtin_amdgcn_s_setprio(0);
        }
        lsum += __shfl_xor(lsum, 16);
        lsum += __shfl_xor(lsum, 32);
        l_run += lsum;

        __syncthreads();
    }

    // ---- epilogue ----
#pragma unroll
    for (int r = 0; r < 4; ++r) {
        const float linv = 1.f / __shfl(l_run, l4 * 4 + r);
        const size_t orow = bbase + (size_t)(qb0 + w * 16 + l4 * 4 + r) * 1024;
#pragma unroll
        for (int g = 0; g < 4; ++g)
            Ob[orow + g * 16 + lm] = f2bf(oacc[g][r] * linv);
    }
}

extern "C" void kernel_launch(void* const* d_in, const int* in_sizes, int n_in,
                              void* d_out, int out_size, void* d_ws, size_t ws_size,
                              hipStream_t stream)
{
    const float* query = (const float*)d_in[0];
    const float* value = (const float*)d_in[1];
    const float* key   = (const float*)d_in[2];
    const float* Wq = (const float*)d_in[3];
    const float* bq = (const float*)d_in[4];
    const float* Wk = (const float*)d_in[5];
    const float* bk = (const float*)d_in[6];
    const float* Wv = (const float*)d_in[7];
    const float* bv = (const float*)d_in[8];
    const float* Wo = (const float*)d_in[9];
    const float* bo = (const float*)d_in[10];
    float* out = (float*)d_out;

    const int M = 2 * 2048;
    const int E = 1024;
    const size_t act = (size_t)M * E;

    u16* Qb  = (u16*)d_ws;
    u16* Kb  = Qb + act;
    u16* Vtb = Kb + act;   // V^T in [B, E, T] layout
    u16* Ab  = Vtb + act;

    // q pre-scaled by (1/sqrt(D)) * log2(e): softmax runs on raw v_exp_f32
    const float SCALE_Q = 0.125f * 1.4426950408889634f;

    // Q/K/V projections, fp32 inputs, fused conversion (z=2 emits V^T)
    GemmArgs gq;
    gq.A[0] = query; gq.W[0] = Wq;    gq.bias[0] = bq; gq.C[0] = Qb;  gq.scale[0] = SCALE_Q; gq.trans[0] = 0;
    gq.A[1] = key;   gq.W[1] = Wk;    gq.bias[1] = bk; gq.C[1] = Kb;  gq.scale[1] = 1.0f;    gq.trans[1] = 0;
    gq.A[2] = Wv;    gq.W[2] = value; gq.bias[2] = bv; gq.C[2] = Vtb; gq.scale[2] = 1.0f;    gq.trans[2] = 1;
    dim3 ggrid(E / 128, M / 128, 3);
    hipLaunchKernelGGL((gemm_nt_mfma<true, true>), ggrid, dim3(256), 0, stream, gq, M, E, E);

    // flash attention -> Ab (bf16), XCD-swizzled 1D grid
    hipLaunchKernelGGL(flash_attn_mfma6, dim3(512), dim3(512), 0, stream, Qb, Kb, Vtb, Ab);

    // output projection: A = Ab (bf16), W = Wo (fp32), fp32 out
    GemmArgs go;
    go.A[0] = Ab; go.W[0] = Wo; go.bias[0] = bo; go.C[0] = out; go.scale[0] = 1.0f; go.trans[0] = 0;
    go.A[1] = Ab; go.W[1] = Wo; go.bias[1] = bo; go.C[1] = out; go.scale[1] = 1.0f; go.trans[1] = 0;
    go.A[2] = Ab; go.W[2] = Wo; go.bias[2] = bo; go.C[2] = out; go.scale[2] = 1.0f; go.trans[2] = 0;
    dim3 ogrid(E / 128, M / 128, 1);
    hipLaunchKernelGGL((gemm_nt_mfma<false, false>), ogrid, dim3(256), 0, stream, go, M, E, E);
}

// Round 9
// 149.713 us; speedup vs baseline: 1.1795x; 1.0340x over previous
//
#include <hip/hip_runtime.h>
#include <math.h>

// Problem constants: B=2, S=T=2048, E=1024, H=16, D=64
typedef __attribute__((ext_vector_type(8))) short short8;
typedef __attribute__((ext_vector_type(4))) float f32x4;
typedef unsigned short u16;

// fp32 -> bf16 round-to-nearest-even (finite inputs)
__device__ __forceinline__ u16 f2bf(float x) {
    unsigned int u = __float_as_uint(x);
    u += 0x7FFFu + ((u >> 16) & 1u);
    return (u16)(u >> 16);
}

// packed fp32x2 -> bf16x2, single instruction; no builtin on gfx950
__device__ __forceinline__ unsigned cvt_pk_bf16(float lo, float hi) {
    unsigned r;
    asm("v_cvt_pk_bf16_f32 %0, %1, %2" : "=v"(r) : "v"(lo), "v"(hi));
    return r;
}

__device__ __forceinline__ void load_lds16(const void* g, void* l) {
    __builtin_amdgcn_global_load_lds(
        (const __attribute__((address_space(1))) unsigned int*)g,
        (__attribute__((address_space(3))) unsigned int*)l,
        16, 0, 0);
}

// ---------------------------------------------------------------------------
// Batched fp32 -> bf16 convert (7 tensors). Measured at HBM BW floor (~6 TB/s).
// ---------------------------------------------------------------------------
struct CvtArgs {
    const float* src[7];
    u16* dst[7];
    int n8[7];
};

__global__ __launch_bounds__(256) void cvt_bf16(CvtArgs c) {
    const int z = blockIdx.z;
    const int i = blockIdx.x * 256 + threadIdx.x;
    if (i >= c.n8[z]) return;
    const float4* s = (const float4*)c.src[z];
    const float4 a = s[2 * i];
    const float4 b = s[2 * i + 1];
    union { short8 v; unsigned u[4]; } o;
    o.u[0] = cvt_pk_bf16(a.x, a.y);
    o.u[1] = cvt_pk_bf16(a.z, a.w);
    o.u[2] = cvt_pk_bf16(b.x, b.y);
    o.u[3] = cvt_pk_bf16(b.z, b.w);
    ((short8*)c.dst[z])[i] = o.v;
}

// ---------------------------------------------------------------------------
// bf16 MFMA GEMM: normal mode:   C[M,N] = (A @ W^T + bias) * scale
//                 trans mode(z): C^T into [b][dim][t] layout (A=weights,
//                 W=activations; D[row=dim][col=token]).
// m97-style: 128x128 tile, BK=32, 4 waves, global_load_lds staging.
// 1D grid, XCD-aware decode: id = sl*8 + xcd; each XCD owns 4 contiguous
// M-tiles x all 8 N-tiles -> W panel L2-resident, A panels single-XCD.
// ---------------------------------------------------------------------------
struct GemmArgs {
    const u16* A[3];
    const u16* W[3];
    const float* bias[3];
    void* C[3];
    float scale[3];
    int trans[3];
};

template <bool BF16OUT>
__global__ __launch_bounds__(256) void gemm_nt_mfma(GemmArgs ga, int M, int N, int K)
{
    __shared__ u16 As[128 * 32];
    __shared__ u16 Bs[128 * 32];
    const int z = blockIdx.z;
    const u16* __restrict__ A = ga.A[z];
    const u16* __restrict__ W = ga.W[z];
    const float* __restrict__ bias = ga.bias[z];
    const float scale = ga.scale[z];
    const int trans = ga.trans[z];

    const int tid = threadIdx.x;
    const int w = tid >> 6, l = tid & 63;
    const int l4 = l >> 4, lm = l & 15;
    const int wr = w >> 1, wc = w & 1;

    // XCD-aware decode: 256 blocks/z; xcd owns bmi in [xcd*4, xcd*4+4)
    const int idx = blockIdx.x;
    const int xcd = idx & 7;
    const int sl  = idx >> 3;              // 0..31
    const int bmi = xcd * 4 + (sl & 3);    // 0..31 (M=4096 side)
    const int bni = sl >> 2;               // 0..7  (N=1024 side)
    const int bm = (trans ? bni : bmi) * 128;
    const int bn = (trans ? bmi : bni) * 128;

    const int srow = l >> 2;
    const int sseg = l & 3;

    f32x4 acc[4][4];
#pragma unroll
    for (int m = 0; m < 4; ++m)
#pragma unroll
        for (int n = 0; n < 4; ++n) acc[m][n] = (f32x4){0.f, 0.f, 0.f, 0.f};

    for (int k0 = 0; k0 < K; k0 += 32) {
        __syncthreads();
#pragma unroll
        for (int i = 0; i < 2; ++i) {
            const int blk = w * 2 + i;
            const int row = blk * 16 + srow;
            load_lds16(A + (size_t)(bm + row) * K + k0 + sseg * 8,
                       (char*)As + blk * 1024);
            load_lds16(W + (size_t)(bn + row) * K + k0 + sseg * 8,
                       (char*)Bs + blk * 1024);
        }
        __syncthreads();

        short8 af[4], bf[4];
#pragma unroll
        for (int m = 0; m < 4; ++m)
            af[m] = *(const short8*)&As[(wr * 64 + m * 16 + lm) * 32 + l4 * 8];
#pragma unroll
        for (int n = 0; n < 4; ++n)
            bf[n] = *(const short8*)&Bs[(wc * 64 + n * 16 + lm) * 32 + l4 * 8];
#pragma unroll
        for (int m = 0; m < 4; ++m)
#pragma unroll
            for (int n = 0; n < 4; ++n)
                acc[m][n] = __builtin_amdgcn_mfma_f32_16x16x32_bf16(af[m], bf[n], acc[m][n], 0, 0, 0);
    }

    if (!trans) {
        float bv[4];
#pragma unroll
        for (int n = 0; n < 4; ++n) bv[n] = bias[bn + wc * 64 + n * 16 + lm];
#pragma unroll
        for (int m = 0; m < 4; ++m) {
#pragma unroll
            for (int n = 0; n < 4; ++n) {
                const int col = bn + wc * 64 + n * 16 + lm;
#pragma unroll
                for (int r = 0; r < 4; ++r) {
                    const int row = bm + wr * 64 + m * 16 + l4 * 4 + r;
                    const float v = (acc[m][n][r] + bv[n]) * scale;
                    if (BF16OUT)
                        ((u16*)ga.C[z])[(size_t)row * N + col] = f2bf(v);
                    else
                        ((float*)ga.C[z])[(size_t)row * N + col] = v;
                }
            }
        }
    } else {
#pragma unroll
        for (int m = 0; m < 4; ++m) {
            const float4 bv4 = *(const float4*)(bias + bm + wr * 64 + m * 16 + l4 * 4);
            const float bvr[4] = {bv4.x, bv4.y, bv4.z, bv4.w};
#pragma unroll
            for (int n = 0; n < 4; ++n) {
                const int col = bn + wc * 64 + n * 16 + lm;            // token
                const size_t cbase = (size_t)(col >> 11) * 2097152 + (size_t)(col & 2047);
#pragma unroll
                for (int r = 0; r < 4; ++r) {
                    const int row = bm + wr * 64 + m * 16 + l4 * 4 + r; // dim
                    const float v = (acc[m][n][r] + bvr[r]) * scale;
                    ((u16*)ga.C[z])[cbase + (size_t)row * 2048] = f2bf(v);
                }
            }
        }
    }
}

// ---------------------------------------------------------------------------
// Flash attention v6 (R8-verified): 8 waves (512 thr), QBLK=128 (16 q/wave),
// KVBLK=128 (16 iters, 1 barrier each). Swapped QK^T in exp2 domain (Q
// pre-scaled by 0.125*log2e). K[128][64] and V^T[64][128] double-buffered via
// global_load_lds with pre-swizzled per-lane sources. PV split into two
// 64-key halves reusing a 64-wide per-wave P buffer. setprio around MFMA.
// 1D grid, bijective XCD decode: each XCD owns 4 (b,h) groups.
// ---------------------------------------------------------------------------
__global__ __launch_bounds__(512, 4) void flash_attn_mfma6(
    const u16* __restrict__ Qb, const u16* __restrict__ Kb,
    const u16* __restrict__ Vt, u16* __restrict__ Ob)
{
    __shared__ u16 Ks[2][128 * 64];   // [key][d-chunk ^ (key&7)]
    __shared__ u16 Vs[2][64 * 128];   // [d][key-chunk ^ (d&7)], chunk 4-bit
    __shared__ u16 Ps[8][16 * 64];    // per-wave [q][key-chunk4 ^ (2*(q&7))]

    const int tid = threadIdx.x;
    const int w  = tid >> 6;     // 0..7
    const int l  = tid & 63;
    const int l4 = l >> 4;
    const int lm = l & 15;

    const int id = blockIdx.x;
    const int xcd = id & 7;
    const int s = id >> 3;
    const int qt = s & 15;
    const int g0 = (s >> 4) * 8 + xcd;   // 0..31 = (b,h) group
    const int h = g0 & 15;
    const int b = g0 >> 4;
    const int qb0 = qt << 7;

    const size_t bbase = (size_t)b * 2048 * 1024 + (size_t)h * 64;       // [B,S,E]
    const size_t vbase = (size_t)b * 2097152 + (size_t)(h * 64) * 2048;  // [B,E,T]

    short8 qf[2];
    {
        const u16* qrow = Qb + bbase + (size_t)(qb0 + w * 16 + lm) * 1024;
        qf[0] = *(const short8*)(qrow + l4 * 8);
        qf[1] = *(const short8*)(qrow + 32 + l4 * 8);
    }

    auto stageK = [&](int t0, int bufi) {
#pragma unroll
        for (int ii = 0; ii < 2; ++ii) {
            const int i = w * 2 + ii;
            const int key = i * 8 + (l >> 3);
            const int chunk = (l & 7) ^ ((l >> 3) & 7);
            load_lds16(Kb + bbase + (size_t)(t0 + key) * 1024 + chunk * 8,
                       (char*)&Ks[bufi][0] + i * 1024);
        }
    };
    auto stageV = [&](int t0, int bufi) {
#pragma unroll
        for (int ii = 0; ii < 2; ++ii) {
            const int i = w * 2 + ii;
            const int d = i * 4 + (l >> 4);
            const int chunk = (l & 15) ^ (d & 7);
            load_lds16(Vt + vbase + (size_t)d * 2048 + t0 + chunk * 8,
                       (char*)&Vs[bufi][0] + i * 1024);
        }
    };

    f32x4 oacc[4];
#pragma unroll
    for (int g = 0; g < 4; ++g) oacc[g] = (f32x4){0.f, 0.f, 0.f, 0.f};
    float m_run = -1e30f;
    float l_run = 0.f;

    stageK(0, 0);
    stageV(0, 0);
    __syncthreads();

    for (int t = 0; t < 16; ++t) {
        const int buf = t & 1;
        if (t < 15) {
            stageK((t + 1) * 128, buf ^ 1);
            stageV((t + 1) * 128, buf ^ 1);
        }

        // ---- QK^T (swapped): lane holds S[key=16g+4*l4+r][q=lm] ----
        f32x4 sacc[8];
#pragma unroll
        for (int g = 0; g < 8; ++g) sacc[g] = (f32x4){0.f, 0.f, 0.f, 0.f};
        __builtin_amdgcn_s_setprio(1);
#pragma unroll
        for (int g = 0; g < 8; ++g) {
#pragma unroll
            for (int c = 0; c < 2; ++c) {
                const short8 kf = *(const short8*)
                    &Ks[buf][(16 * g + lm) * 64 + (((4 * c + l4) ^ (lm & 7)) << 3)];
                sacc[g] = __builtin_amdgcn_mfma_f32_16x16x32_bf16(kf, qf[c], sacc[g], 0, 0, 0);
            }
        }
        __builtin_amdgcn_s_setprio(0);

        // ---- softmax (log2 domain): 32 in-lane scores + 2 shfl ----
        float amax[8];
#pragma unroll
        for (int g = 0; g < 8; ++g)
            amax[g] = fmaxf(fmaxf(sacc[g][0], sacc[g][1]), fmaxf(sacc[g][2], sacc[g][3]));
        float mt = fmaxf(fmaxf(fmaxf(amax[0], amax[1]), fmaxf(amax[2], amax[3])),
                         fmaxf(fmaxf(amax[4], amax[5]), fmaxf(amax[6], amax[7])));
        mt = fmaxf(mt, __shfl_xor(mt, 16));
        mt = fmaxf(mt, __shfl_xor(mt, 32));

        const bool resc = !__all(mt <= m_run);
        if (resc) {
            const float mn = fmaxf(m_run, mt);
            const float alpha = __builtin_amdgcn_exp2f(m_run - mn);
            m_run = mn;
            l_run *= alpha;
#pragma unroll
            for (int r = 0; r < 4; ++r) {
                const float a = __shfl(alpha, l4 * 4 + r);
#pragma unroll
                for (int g = 0; g < 4; ++g) oacc[g][r] *= a;
            }
        }

        float lsum = 0.f;
        const float mr = m_run;
#pragma unroll
        for (int hh = 0; hh < 2; ++hh) {
#pragma unroll
            for (int gg = 0; gg < 4; ++gg) {
                const int g = hh * 4 + gg;
                const float p0 = __builtin_amdgcn_exp2f(sacc[g][0] - mr);
                const float p1 = __builtin_amdgcn_exp2f(sacc[g][1] - mr);
                const float p2 = __builtin_amdgcn_exp2f(sacc[g][2] - mr);
                const float p3 = __builtin_amdgcn_exp2f(sacc[g][3] - mr);
                lsum += (p0 + p1) + (p2 + p3);
                uint2 pk;
                pk.x = cvt_pk_bf16(p0, p1);
                pk.y = cvt_pk_bf16(p2, p3);
                *(uint2*)&Ps[w][lm * 64 + (((gg * 4 + l4) ^ ((lm & 7) << 1)) << 2)] = pk;
            }
            __builtin_amdgcn_s_setprio(1);
#pragma unroll
            for (int c = 0; c < 2; ++c) {
                const short8 pa = *(const short8*)
                    &Ps[w][lm * 64 + (((c * 8 + l4 * 2) ^ ((lm & 7) << 1)) << 2)];
#pragma unroll
                for (int g = 0; g < 4; ++g) {
                    const int d = 16 * g + lm;
                    const short8 vf = *(const short8*)
                        &Vs[buf][d * 128 + (((hh * 8 + c * 4 + l4) ^ (d & 7)) << 3)];
                    oacc[g] = __builtin_amdgcn_mfma_f32_16x16x32_bf16(pa, vf, oacc[g], 0, 0, 0);
                }
            }
            __builtin_amdgcn_s_setprio(0);
        }
        lsum += __shfl_xor(lsum, 16);
        lsum += __shfl_xor(lsum, 32);
        l_run += lsum;

        __syncthreads();
    }

    // ---- epilogue ----
#pragma unroll
    for (int r = 0; r < 4; ++r) {
        const float linv = 1.f / __shfl(l_run, l4 * 4 + r);
        const size_t orow = bbase + (size_t)(qb0 + w * 16 + l4 * 4 + r) * 1024;
#pragma unroll
        for (int g = 0; g < 4; ++g)
            Ob[orow + g * 16 + lm] = f2bf(oacc[g][r] * linv);
    }
}

extern "C" void kernel_launch(void* const* d_in, const int* in_sizes, int n_in,
                              void* d_out, int out_size, void* d_ws, size_t ws_size,
                              hipStream_t stream)
{
    const float* query = (const float*)d_in[0];
    const float* value = (const float*)d_in[1];
    const float* key   = (const float*)d_in[2];
    const float* Wq = (const float*)d_in[3];
    const float* bq = (const float*)d_in[4];
    const float* Wk = (const float*)d_in[5];
    const float* bk = (const float*)d_in[6];
    const float* Wv = (const float*)d_in[7];
    const float* bv = (const float*)d_in[8];
    const float* Wo = (const float*)d_in[9];
    const float* bo = (const float*)d_in[10];
    float* out = (float*)d_out;

    const int M = 2 * 2048;
    const int E = 1024;
    const size_t act = (size_t)M * E;
    const size_t wel = (size_t)E * E;

    u16* qc  = (u16*)d_ws;
    u16* kc  = qc + act;
    u16* vc  = kc + act;
    u16* wqb = vc + act;
    u16* wkb = wqb + wel;
    u16* wvb = wkb + wel;
    u16* wob = wvb + wel;
    u16* Qb  = wob + wel;
    u16* Kb  = Qb + act;
    u16* Vtb = Kb + act;   // V^T in [B, E, T] layout
    u16* Ab  = Vtb + act;

    CvtArgs ca;
    ca.src[0] = query; ca.dst[0] = qc;  ca.n8[0] = (int)(act / 8);
    ca.src[1] = key;   ca.dst[1] = kc;  ca.n8[1] = (int)(act / 8);
    ca.src[2] = value; ca.dst[2] = vc;  ca.n8[2] = (int)(act / 8);
    ca.src[3] = Wq;    ca.dst[3] = wqb; ca.n8[3] = (int)(wel / 8);
    ca.src[4] = Wk;    ca.dst[4] = wkb; ca.n8[4] = (int)(wel / 8);
    ca.src[5] = Wv;    ca.dst[5] = wvb; ca.n8[5] = (int)(wel / 8);
    ca.src[6] = Wo;    ca.dst[6] = wob; ca.n8[6] = (int)(wel / 8);
    dim3 cgrid((unsigned)((act / 8 + 255) / 256), 1, 7);
    hipLaunchKernelGGL(cvt_bf16, cgrid, dim3(256), 0, stream, ca);

    // q pre-scaled by (1/sqrt(D)) * log2(e): softmax runs on raw v_exp_f32
    const float SCALE_Q = 0.125f * 1.4426950408889634f;

    GemmArgs gq;
    gq.A[0] = qc;  gq.W[0] = wqb; gq.bias[0] = bq; gq.C[0] = Qb;  gq.scale[0] = SCALE_Q; gq.trans[0] = 0;
    gq.A[1] = kc;  gq.W[1] = wkb; gq.bias[1] = bk; gq.C[1] = Kb;  gq.scale[1] = 1.0f;    gq.trans[1] = 0;
    gq.A[2] = wvb; gq.W[2] = vc;  gq.bias[2] = bv; gq.C[2] = Vtb; gq.scale[2] = 1.0f;    gq.trans[2] = 1;
    hipLaunchKernelGGL((gemm_nt_mfma<true>), dim3(256, 1, 3), dim3(256), 0, stream, gq, M, E, E);

    // flash attention -> Ab (bf16), XCD-swizzled 1D grid
    hipLaunchKernelGGL(flash_attn_mfma6, dim3(512), dim3(512), 0, stream, Qb, Kb, Vtb, Ab);

    GemmArgs go;
    go.A[0] = Ab; go.W[0] = wob; go.bias[0] = bo; go.C[0] = out; go.scale[0] = 1.0f; go.trans[0] = 0;
    go.A[1] = Ab; go.W[1] = wob; go.bias[1] = bo; go.C[1] = out; go.scale[1] = 1.0f; go.trans[1] = 0;
    go.A[2] = Ab; go.W[2] = wob; go.bias[2] = bo; go.C[2] = out; go.scale[2] = 1.0f; go.trans[2] = 0;
    hipLaunchKernelGGL((gemm_nt_mfma<false>), dim3(256, 1, 1), dim3(256), 0, stream, go, M, E, E);
}

// Round 10
// 146.907 us; speedup vs baseline: 1.2021x; 1.0191x over previous
//
#include <hip/hip_runtime.h>
#include <math.h>

// Problem constants: B=2, S=T=2048, E=1024, H=16, D=64
typedef __attribute__((ext_vector_type(8))) short short8;
typedef __attribute__((ext_vector_type(4))) float f32x4;
typedef unsigned short u16;

// fp32 -> bf16 round-to-nearest-even (finite inputs)
__device__ __forceinline__ u16 f2bf(float x) {
    unsigned int u = __float_as_uint(x);
    u += 0x7FFFu + ((u >> 16) & 1u);
    return (u16)(u >> 16);
}

// packed fp32x2 -> bf16x2, single instruction; no builtin on gfx950
__device__ __forceinline__ unsigned cvt_pk_bf16(float lo, float hi) {
    unsigned r;
    asm("v_cvt_pk_bf16_f32 %0, %1, %2" : "=v"(r) : "v"(lo), "v"(hi));
    return r;
}

__device__ __forceinline__ void load_lds16(const void* g, void* l) {
    __builtin_amdgcn_global_load_lds(
        (const __attribute__((address_space(1))) unsigned int*)g,
        (__attribute__((address_space(3))) unsigned int*)l,
        16, 0, 0);
}

// ---------------------------------------------------------------------------
// Batched fp32 -> bf16 convert (7 tensors). Measured at HBM BW floor (~6 TB/s).
// ---------------------------------------------------------------------------
struct CvtArgs {
    const float* src[7];
    u16* dst[7];
    int n8[7];
};

__global__ __launch_bounds__(256) void cvt_bf16(CvtArgs c) {
    const int z = blockIdx.z;
    const int i = blockIdx.x * 256 + threadIdx.x;
    if (i >= c.n8[z]) return;
    const float4* s = (const float4*)c.src[z];
    const float4 a = s[2 * i];
    const float4 b = s[2 * i + 1];
    union { short8 v; unsigned u[4]; } o;
    o.u[0] = cvt_pk_bf16(a.x, a.y);
    o.u[1] = cvt_pk_bf16(a.z, a.w);
    o.u[2] = cvt_pk_bf16(b.x, b.y);
    o.u[3] = cvt_pk_bf16(b.z, b.w);
    ((short8*)c.dst[z])[i] = o.v;
}

// ---------------------------------------------------------------------------
// bf16 MFMA GEMM: normal mode:   C[M,N] = (A @ W^T + bias) * scale
//                 trans mode(z): C^T into [b][dim][t] layout (A=weights,
//                 W=activations; D[row=dim][col=token]).
// m97-style: 128x128 tile, BK=32, 4 waves, global_load_lds staging.
// 1D grid, XCD-aware decode (R9-verified).
// ---------------------------------------------------------------------------
struct GemmArgs {
    const u16* A[3];
    const u16* W[3];
    const float* bias[3];
    void* C[3];
    float scale[3];
    int trans[3];
};

template <bool BF16OUT>
__global__ __launch_bounds__(256) void gemm_nt_mfma(GemmArgs ga, int M, int N, int K)
{
    __shared__ u16 As[128 * 32];
    __shared__ u16 Bs[128 * 32];
    const int z = blockIdx.z;
    const u16* __restrict__ A = ga.A[z];
    const u16* __restrict__ W = ga.W[z];
    const float* __restrict__ bias = ga.bias[z];
    const float scale = ga.scale[z];
    const int trans = ga.trans[z];

    const int tid = threadIdx.x;
    const int w = tid >> 6, l = tid & 63;
    const int l4 = l >> 4, lm = l & 15;
    const int wr = w >> 1, wc = w & 1;

    const int idx = blockIdx.x;
    const int xcd = idx & 7;
    const int sl  = idx >> 3;
    const int bmi = xcd * 4 + (sl & 3);
    const int bni = sl >> 2;
    const int bm = (trans ? bni : bmi) * 128;
    const int bn = (trans ? bmi : bni) * 128;

    const int srow = l >> 2;
    const int sseg = l & 3;

    f32x4 acc[4][4];
#pragma unroll
    for (int m = 0; m < 4; ++m)
#pragma unroll
        for (int n = 0; n < 4; ++n) acc[m][n] = (f32x4){0.f, 0.f, 0.f, 0.f};

    for (int k0 = 0; k0 < K; k0 += 32) {
        __syncthreads();
#pragma unroll
        for (int i = 0; i < 2; ++i) {
            const int blk = w * 2 + i;
            const int row = blk * 16 + srow;
            load_lds16(A + (size_t)(bm + row) * K + k0 + sseg * 8,
                       (char*)As + blk * 1024);
            load_lds16(W + (size_t)(bn + row) * K + k0 + sseg * 8,
                       (char*)Bs + blk * 1024);
        }
        __syncthreads();

        short8 af[4], bf[4];
#pragma unroll
        for (int m = 0; m < 4; ++m)
            af[m] = *(const short8*)&As[(wr * 64 + m * 16 + lm) * 32 + l4 * 8];
#pragma unroll
        for (int n = 0; n < 4; ++n)
            bf[n] = *(const short8*)&Bs[(wc * 64 + n * 16 + lm) * 32 + l4 * 8];
#pragma unroll
        for (int m = 0; m < 4; ++m)
#pragma unroll
            for (int n = 0; n < 4; ++n)
                acc[m][n] = __builtin_amdgcn_mfma_f32_16x16x32_bf16(af[m], bf[n], acc[m][n], 0, 0, 0);
    }

    if (!trans) {
        float bv[4];
#pragma unroll
        for (int n = 0; n < 4; ++n) bv[n] = bias[bn + wc * 64 + n * 16 + lm];
#pragma unroll
        for (int m = 0; m < 4; ++m) {
#pragma unroll
            for (int n = 0; n < 4; ++n) {
                const int col = bn + wc * 64 + n * 16 + lm;
#pragma unroll
                for (int r = 0; r < 4; ++r) {
                    const int row = bm + wr * 64 + m * 16 + l4 * 4 + r;
                    const float v = (acc[m][n][r] + bv[n]) * scale;
                    if (BF16OUT)
                        ((u16*)ga.C[z])[(size_t)row * N + col] = f2bf(v);
                    else
                        ((float*)ga.C[z])[(size_t)row * N + col] = v;
                }
            }
        }
    } else {
#pragma unroll
        for (int m = 0; m < 4; ++m) {
            const float4 bv4 = *(const float4*)(bias + bm + wr * 64 + m * 16 + l4 * 4);
            const float bvr[4] = {bv4.x, bv4.y, bv4.z, bv4.w};
#pragma unroll
            for (int n = 0; n < 4; ++n) {
                const int col = bn + wc * 64 + n * 16 + lm;            // token
                const size_t cbase = (size_t)(col >> 11) * 2097152 + (size_t)(col & 2047);
#pragma unroll
                for (int r = 0; r < 4; ++r) {
                    const int row = bm + wr * 64 + m * 16 + l4 * 4 + r; // dim
                    const float v = (acc[m][n][r] + bvr[r]) * scale;
                    ((u16*)ga.C[z])[cbase + (size_t)row * 2048] = f2bf(v);
                }
            }
        }
    }
}

// ---------------------------------------------------------------------------
// Flash attention v7: v6 + in-register P redistribution via permlane swaps
// (no P LDS roundtrip) + defer-rescale THR=8 (log2 domain).
//
// After swapped QK^T, lane (l4,lm) holds P[key=16g+4*l4+r][q=lm] packed as
// up[g]=bf16x2(r0,r1), vp[g]=bf16x2(r2,r3). The PV A-frag for k-block kb
// (keys 32kb+8*l4+j, q=lm) is a 4x4 u32 block-transpose across l4 groups:
//   (w0,w2) = permlane16_swap(permlane32_swap(up[2kb], up[2kb+1]))
//   (w1,w3) = permlane16_swap(permlane32_swap(vp[2kb], vp[2kb+1]))
// pl32: vdst.hi32 <-> vsrc.lo32 ; pl16: vdst rows 1,3 <-> vsrc rows 0,2.
// ---------------------------------------------------------------------------
__global__ __launch_bounds__(512, 4) void flash_attn_mfma7(
    const u16* __restrict__ Qb, const u16* __restrict__ Kb,
    const u16* __restrict__ Vt, u16* __restrict__ Ob)
{
    __shared__ u16 Ks[2][128 * 64];   // [key][d-chunk ^ (key&7)]
    __shared__ u16 Vs[2][64 * 128];   // [d][key-chunk ^ (d&7)], 4-bit chunk

    const int tid = threadIdx.x;
    const int w  = tid >> 6;     // 0..7
    const int l  = tid & 63;
    const int l4 = l >> 4;
    const int lm = l & 15;

    const int id = blockIdx.x;
    const int xcd = id & 7;
    const int s = id >> 3;
    const int qt = s & 15;
    const int g0 = (s >> 4) * 8 + xcd;   // 0..31 = (b,h) group
    const int h = g0 & 15;
    const int b = g0 >> 4;
    const int qb0 = qt << 7;

    const size_t bbase = (size_t)b * 2048 * 1024 + (size_t)h * 64;       // [B,S,E]
    const size_t vbase = (size_t)b * 2097152 + (size_t)(h * 64) * 2048;  // [B,E,T]

    short8 qf[2];
    {
        const u16* qrow = Qb + bbase + (size_t)(qb0 + w * 16 + lm) * 1024;
        qf[0] = *(const short8*)(qrow + l4 * 8);
        qf[1] = *(const short8*)(qrow + 32 + l4 * 8);
    }

    auto stageK = [&](int t0, int bufi) {
#pragma unroll
        for (int ii = 0; ii < 2; ++ii) {
            const int i = w * 2 + ii;
            const int key = i * 8 + (l >> 3);
            const int chunk = (l & 7) ^ ((l >> 3) & 7);
            load_lds16(Kb + bbase + (size_t)(t0 + key) * 1024 + chunk * 8,
                       (char*)&Ks[bufi][0] + i * 1024);
        }
    };
    auto stageV = [&](int t0, int bufi) {
#pragma unroll
        for (int ii = 0; ii < 2; ++ii) {
            const int i = w * 2 + ii;
            const int d = i * 4 + (l >> 4);
            const int chunk = (l & 15) ^ (d & 7);
            load_lds16(Vt + vbase + (size_t)d * 2048 + t0 + chunk * 8,
                       (char*)&Vs[bufi][0] + i * 1024);
        }
    };

    f32x4 oacc[4];
#pragma unroll
    for (int g = 0; g < 4; ++g) oacc[g] = (f32x4){0.f, 0.f, 0.f, 0.f};
    float m_run = -1e30f;
    float l_run = 0.f;

    stageK(0, 0);
    stageV(0, 0);
    __syncthreads();

    for (int t = 0; t < 16; ++t) {
        const int buf = t & 1;
        if (t < 15) {
            stageK((t + 1) * 128, buf ^ 1);
            stageV((t + 1) * 128, buf ^ 1);
        }

        // ---- QK^T (swapped): lane holds S[key=16g+4*l4+r][q=lm] ----
        f32x4 sacc[8];
#pragma unroll
        for (int g = 0; g < 8; ++g) sacc[g] = (f32x4){0.f, 0.f, 0.f, 0.f};
        __builtin_amdgcn_s_setprio(1);
#pragma unroll
        for (int g = 0; g < 8; ++g) {
#pragma unroll
            for (int c = 0; c < 2; ++c) {
                const short8 kf = *(const short8*)
                    &Ks[buf][(16 * g + lm) * 64 + (((4 * c + l4) ^ (lm & 7)) << 3)];
                sacc[g] = __builtin_amdgcn_mfma_f32_16x16x32_bf16(kf, qf[c], sacc[g], 0, 0, 0);
            }
        }
        __builtin_amdgcn_s_setprio(0);

        // ---- softmax (log2 domain): 32 in-lane scores + 2 shfl ----
        float amax[8];
#pragma unroll
        for (int g = 0; g < 8; ++g)
            amax[g] = fmaxf(fmaxf(sacc[g][0], sacc[g][1]), fmaxf(sacc[g][2], sacc[g][3]));
        float mt = fmaxf(fmaxf(fmaxf(amax[0], amax[1]), fmaxf(amax[2], amax[3])),
                         fmaxf(fmaxf(amax[4], amax[5]), fmaxf(amax[6], amax[7])));
        mt = fmaxf(mt, __shfl_xor(mt, 16));
        mt = fmaxf(mt, __shfl_xor(mt, 32));

        // defer-rescale: tolerate P up to 2^8 (bf16 is scale-free)
        const bool resc = !__all(mt <= m_run + 8.0f);
        if (resc) {
            const float mn = fmaxf(m_run, mt);
            const float alpha = __builtin_amdgcn_exp2f(m_run - mn);
            m_run = mn;
            l_run *= alpha;
#pragma unroll
            for (int r = 0; r < 4; ++r) {
                const float a = __shfl(alpha, l4 * 4 + r);
#pragma unroll
                for (int g = 0; g < 4; ++g) oacc[g][r] *= a;
            }
        }

        // ---- P = exp2(S - m), packed bf16x2 in-register ----
        float lsum = 0.f;
        const float mr = m_run;
        unsigned up[8], vp[8];
#pragma unroll
        for (int g = 0; g < 8; ++g) {
            const float p0 = __builtin_amdgcn_exp2f(sacc[g][0] - mr);
            const float p1 = __builtin_amdgcn_exp2f(sacc[g][1] - mr);
            const float p2 = __builtin_amdgcn_exp2f(sacc[g][2] - mr);
            const float p3 = __builtin_amdgcn_exp2f(sacc[g][3] - mr);
            lsum += (p0 + p1) + (p2 + p3);
            up[g] = cvt_pk_bf16(p0, p1);
            vp[g] = cvt_pk_bf16(p2, p3);
        }
        lsum += __shfl_xor(lsum, 16);
        lsum += __shfl_xor(lsum, 32);
        l_run += lsum;

        // ---- PV: A-frag via permlane swaps; B via swizzled b128 ----
#pragma unroll
        for (int kb = 0; kb < 4; ++kb) {
            unsigned w0 = up[2 * kb], w2 = up[2 * kb + 1];
            unsigned w1 = vp[2 * kb], w3 = vp[2 * kb + 1];
            asm("v_permlane32_swap_b32 %0, %1" : "+v"(w0), "+v"(w2));
            asm("v_permlane16_swap_b32 %0, %1" : "+v"(w0), "+v"(w2));
            asm("v_permlane32_swap_b32 %0, %1" : "+v"(w1), "+v"(w3));
            asm("v_permlane16_swap_b32 %0, %1" : "+v"(w1), "+v"(w3));
            union { unsigned u[4]; short8 v8; } pa;
            pa.u[0] = w0; pa.u[1] = w1; pa.u[2] = w2; pa.u[3] = w3;
            __builtin_amdgcn_s_setprio(1);
#pragma unroll
            for (int g = 0; g < 4; ++g) {
                const int d = 16 * g + lm;
                const short8 vf = *(const short8*)
                    &Vs[buf][d * 128 + (((kb * 4 + l4) ^ (d & 7)) << 3)];
                oacc[g] = __builtin_amdgcn_mfma_f32_16x16x32_bf16(pa.v8, vf, oacc[g], 0, 0, 0);
            }
            __builtin_amdgcn_s_setprio(0);
        }

        __syncthreads();
    }

    // ---- epilogue ----
#pragma unroll
    for (int r = 0; r < 4; ++r) {
        const float linv = 1.f / __shfl(l_run, l4 * 4 + r);
        const size_t orow = bbase + (size_t)(qb0 + w * 16 + l4 * 4 + r) * 1024;
#pragma unroll
        for (int g = 0; g < 4; ++g)
            Ob[orow + g * 16 + lm] = f2bf(oacc[g][r] * linv);
    }
}

extern "C" void kernel_launch(void* const* d_in, const int* in_sizes, int n_in,
                              void* d_out, int out_size, void* d_ws, size_t ws_size,
                              hipStream_t stream)
{
    const float* query = (const float*)d_in[0];
    const float* value = (const float*)d_in[1];
    const float* key   = (const float*)d_in[2];
    const float* Wq = (const float*)d_in[3];
    const float* bq = (const float*)d_in[4];
    const float* Wk = (const float*)d_in[5];
    const float* bk = (const float*)d_in[6];
    const float* Wv = (const float*)d_in[7];
    const float* bv = (const float*)d_in[8];
    const float* Wo = (const float*)d_in[9];
    const float* bo = (const float*)d_in[10];
    float* out = (float*)d_out;

    const int M = 2 * 2048;
    const int E = 1024;
    const size_t act = (size_t)M * E;
    const size_t wel = (size_t)E * E;

    u16* qc  = (u16*)d_ws;
    u16* kc  = qc + act;
    u16* vc  = kc + act;
    u16* wqb = vc + act;
    u16* wkb = wqb + wel;
    u16* wvb = wkb + wel;
    u16* wob = wvb + wel;
    u16* Qb  = wob + wel;
    u16* Kb  = Qb + act;
    u16* Vtb = Kb + act;   // V^T in [B, E, T] layout
    u16* Ab  = Vtb + act;

    CvtArgs ca;
    ca.src[0] = query; ca.dst[0] = qc;  ca.n8[0] = (int)(act / 8);
    ca.src[1] = key;   ca.dst[1] = kc;  ca.n8[1] = (int)(act / 8);
    ca.src[2] = value; ca.dst[2] = vc;  ca.n8[2] = (int)(act / 8);
    ca.src[3] = Wq;    ca.dst[3] = wqb; ca.n8[3] = (int)(wel / 8);
    ca.src[4] = Wk;    ca.dst[4] = wkb; ca.n8[4] = (int)(wel / 8);
    ca.src[5] = Wv;    ca.dst[5] = wvb; ca.n8[5] = (int)(wel / 8);
    ca.src[6] = Wo;    ca.dst[6] = wob; ca.n8[6] = (int)(wel / 8);
    dim3 cgrid((unsigned)((act / 8 + 255) / 256), 1, 7);
    hipLaunchKernelGGL(cvt_bf16, cgrid, dim3(256), 0, stream, ca);

    // q pre-scaled by (1/sqrt(D)) * log2(e): softmax runs on raw v_exp_f32
    const float SCALE_Q = 0.125f * 1.4426950408889634f;

    GemmArgs gq;
    gq.A[0] = qc;  gq.W[0] = wqb; gq.bias[0] = bq; gq.C[0] = Qb;  gq.scale[0] = SCALE_Q; gq.trans[0] = 0;
    gq.A[1] = kc;  gq.W[1] = wkb; gq.bias[1] = bk; gq.C[1] = Kb;  gq.scale[1] = 1.0f;    gq.trans[1] = 0;
    gq.A[2] = wvb; gq.W[2] = vc;  gq.bias[2] = bv; gq.C[2] = Vtb; gq.scale[2] = 1.0f;    gq.trans[2] = 1;
    hipLaunchKernelGGL((gemm_nt_mfma<true>), dim3(256, 1, 3), dim3(256), 0, stream, gq, M, E, E);

    // flash attention -> Ab (bf16), XCD-swizzled 1D grid
    hipLaunchKernelGGL(flash_attn_mfma7, dim3(512), dim3(512), 0, stream, Qb, Kb, Vtb, Ab);

    GemmArgs go;
    go.A[0] = Ab; go.W[0] = wob; go.bias[0] = bo; go.C[0] = out; go.scale[0] = 1.0f; go.trans[0] = 0;
    go.A[1] = Ab; go.W[1] = wob; go.bias[1] = bo; go.C[1] = out; go.scale[1] = 1.0f; go.trans[1] = 0;
    go.A[2] = Ab; go.W[2] = wob; go.bias[2] = bo; go.C[2] = out; go.scale[2] = 1.0f; go.trans[2] = 0;
    hipLaunchKernelGGL((gemm_nt_mfma<false>), dim3(256, 1, 1), dim3(256), 0, stream, go, M, E, E);
}